// Round 1
// baseline (284.137 us; speedup 1.0000x reference)
//
#include <hip/hip_runtime.h>
#include <math.h>

#define B_ROWS 16384
#define DLAT   2048
#define NTOT   (2 * B_ROWS)      // 32768 rows
#define NPART  (NTOT / 4)        // 8192 block partials

// K1: one wave (64 lanes) per row; 4 waves per 256-thread block.
// Each lane: 8 x float4 dot-chunks (row is 2048 floats = 8 KiB; wave covers
// 1 KiB per iteration, fully coalesced). Then 6-step shfl_xor reduce.
__global__ __launch_bounds__(256) void k_dot_sig(
    const float* __restrict__ zi, const float* __restrict__ zj,
    const float* __restrict__ W,  const float* __restrict__ bptr,
    float* __restrict__ sp, float* __restrict__ partial)
{
    const int wave = threadIdx.x >> 6;          // 0..3
    const int lane = threadIdx.x & 63;
    const int row  = blockIdx.x * 4 + wave;     // 0..NTOT-1

    const float* zrow = (row < B_ROWS)
        ? (zi + (size_t)row * DLAT)
        : (zj + (size_t)(row - B_ROWS) * DLAT);

    const float4* z4 = (const float4*)zrow;
    const float4* w4 = (const float4*)W;

    float acc = 0.0f;
    #pragma unroll
    for (int it = 0; it < 8; ++it) {
        float4 z = z4[it * 64 + lane];
        float4 w = w4[it * 64 + lane];
        acc += z.x * w.x + z.y * w.y + z.z * w.z + z.w * w.w;
    }

    // wave64 butterfly reduce
    #pragma unroll
    for (int off = 32; off > 0; off >>= 1)
        acc += __shfl_xor(acc, off, 64);

    __shared__ float s4[4];
    if (lane == 0) {
        float pred = acc + bptr[0];
        float spv  = 1.0f / (1.0f + expf(-pred));   // sigmoid(pred)
        sp[row]  = spv;
        s4[wave] = spv;
    }
    __syncthreads();
    if (threadIdx.x == 0)
        partial[blockIdx.x] = (s4[0] + s4[1]) + (s4[2] + s4[3]);
}

// K2: single block. Reduce partials -> total_s_pos, then per-row risk + mean.
__global__ __launch_bounds__(1024) void k_finish(
    const float* __restrict__ sp, const float* __restrict__ partial,
    float* __restrict__ out)
{
    __shared__ float red[1024];
    const int t = threadIdx.x;

    // Phase A: total_s_pos = sum over all rows of sigmoid(pred)
    float tot = 0.0f;
    for (int i = t; i < NPART; i += 1024) tot += partial[i];
    red[t] = tot;
    __syncthreads();
    #pragma unroll
    for (int s = 512; s > 0; s >>= 1) {
        if (t < s) red[t] += red[t + s];
        __syncthreads();
    }
    const float total_s_pos = red[0];
    __syncthreads();

    // constants: PRIOR=0.3, PRIOR_PRIME=0.5, GAMMA=1, BETA=0
    const float c1 = 0.5f / (((float)NTOT - 2.0f) * 0.7f);   // unl coefficient
    const float c2 = (0.5f * 0.3f) / (2.0f * 0.7f);          // pos_inv coefficient

    // Phase B: per-row loss. pair(r) = r ^ B_ROWS. s_neg = 1 - s_pos, so
    // sum_y_pos = 2 - S2, sum_y_pos_inv = S2, sum_y_unl = total - S2.
    float lsum = 0.0f;
    for (int r = t; r < NTOT; r += 1024) {
        float S2  = sp[r] + sp[r ^ B_ROWS];
        float pos = 0.25f * (2.0f - S2);                 // 0.5/2 * (2-S2)
        float neg = c1 * (total_s_pos - S2) - c2 * S2;
        lsum += (neg < 0.0f) ? -neg : (pos + neg);       // nnPU branch
    }
    red[t] = lsum;
    __syncthreads();
    #pragma unroll
    for (int s = 512; s > 0; s >>= 1) {
        if (t < s) red[t] += red[t + s];
        __syncthreads();
    }
    if (t == 0) out[0] = red[0] / (float)NTOT;
}

extern "C" void kernel_launch(void* const* d_in, const int* in_sizes, int n_in,
                              void* d_out, int out_size, void* d_ws, size_t ws_size,
                              hipStream_t stream) {
    const float* zi = (const float*)d_in[0];
    const float* zj = (const float*)d_in[1];
    const float* W  = (const float*)d_in[2];
    const float* b  = (const float*)d_in[3];

    float* sp      = (float*)d_ws;       // 32768 floats
    float* partial = sp + NTOT;          // 8192 floats
    float* out     = (float*)d_out;

    k_dot_sig<<<NTOT / 4, 256, 0, stream>>>(zi, zj, W, b, sp, partial);
    k_finish<<<1, 1024, 0, stream>>>(sp, partial, out);
}

// Round 2
// 280.272 us; speedup vs baseline: 1.0138x; 1.0138x over previous
//
#include <hip/hip_runtime.h>
#include <math.h>

#define B_ROWS 16384
#define DLAT   2048
#define NTOT   (2 * B_ROWS)     // 32768 rows
#define NBLK1  (NTOT / 8)       // 4096 blocks: 4 waves/block, 2 rows/wave
#define NBLK3  128              // loss-partial blocks

// K1: 2 rows per wave. All 16 z float4-loads issued back-to-back (256 B/lane
// of HBM MLP) before any FMA; W chunks come from L1 (8 KB, fully resident).
__global__ __launch_bounds__(256, 4) void k_dot_sig(
    const float* __restrict__ zi, const float* __restrict__ zj,
    const float* __restrict__ W,  const float* __restrict__ bptr,
    float* __restrict__ sp, float* __restrict__ partial)
{
    const int lane = threadIdx.x & 63;
    const int wv   = threadIdx.x >> 6;
    const int r0   = (blockIdx.x * 4 + wv) * 2;
    const int r1   = r0 + 1;

    const float4* pa = (const float4*)((r0 < B_ROWS)
        ? zi + (size_t)r0 * DLAT : zj + (size_t)(r0 - B_ROWS) * DLAT);
    const float4* pb = (const float4*)((r1 < B_ROWS)
        ? zi + (size_t)r1 * DLAT : zj + (size_t)(r1 - B_ROWS) * DLAT);

    float4 za[8], zb[8];
    #pragma unroll
    for (int i = 0; i < 8; ++i) za[i] = pa[i * 64 + lane];
    #pragma unroll
    for (int i = 0; i < 8; ++i) zb[i] = pb[i * 64 + lane];

    const float4* w4 = (const float4*)W;
    float aA = 0.0f, aB = 0.0f;
    #pragma unroll
    for (int i = 0; i < 8; ++i) {
        float4 w = w4[i * 64 + lane];
        aA += za[i].x * w.x + za[i].y * w.y + za[i].z * w.z + za[i].w * w.w;
        aB += zb[i].x * w.x + zb[i].y * w.y + zb[i].z * w.z + zb[i].w * w.w;
    }

    #pragma unroll
    for (int off = 32; off > 0; off >>= 1) {
        aA += __shfl_xor(aA, off, 64);
        aB += __shfl_xor(aB, off, 64);
    }

    __shared__ float s8[8];
    if (lane == 0) {
        float b  = bptr[0];
        float sA = 1.0f / (1.0f + expf(-(aA + b)));
        float sB = 1.0f / (1.0f + expf(-(aB + b)));
        sp[r0] = sA; sp[r1] = sB;
        s8[wv * 2] = sA; s8[wv * 2 + 1] = sB;
    }
    __syncthreads();
    if (threadIdx.x == 0)
        partial[blockIdx.x] = ((s8[0] + s8[1]) + (s8[2] + s8[3]))
                            + ((s8[4] + s8[5]) + (s8[6] + s8[7]));
}

// K2: total_s_pos = sum of 4096 block partials (one block).
__global__ __launch_bounds__(1024) void k_total(
    const float* __restrict__ partial, float* __restrict__ total)
{
    __shared__ float red[1024];
    const int t = threadIdx.x;
    float s = 0.0f;
    for (int i = t; i < NBLK1; i += 1024) s += partial[i];
    red[t] = s;
    __syncthreads();
    #pragma unroll
    for (int st = 512; st > 0; st >>= 1) {
        if (t < st) red[t] += red[t + st];
        __syncthreads();
    }
    if (t == 0) total[0] = red[0];
}

// K3: per-row loss, 128 blocks x 256 threads = 1 row/thread; block partials.
__global__ __launch_bounds__(256) void k_loss(
    const float* __restrict__ sp, const float* __restrict__ total,
    float* __restrict__ lp)
{
    const int t = threadIdx.x;
    const int r = blockIdx.x * 256 + t;

    const float tot = total[0];
    const float c1  = 0.5f / (((float)NTOT - 2.0f) * 0.7f);
    const float c2  = (0.5f * 0.3f) / (2.0f * 0.7f);

    float S2  = sp[r] + sp[r ^ B_ROWS];
    float pos = 0.25f * (2.0f - S2);
    float neg = c1 * (tot - S2) - c2 * S2;
    float l   = (neg < 0.0f) ? -neg : (pos + neg);

    __shared__ float red[256];
    red[t] = l;
    __syncthreads();
    #pragma unroll
    for (int st = 128; st > 0; st >>= 1) {
        if (t < st) red[t] += red[t + st];
        __syncthreads();
    }
    if (t == 0) lp[blockIdx.x] = red[0];
}

// K4: mean over the 128 loss partials.
__global__ __launch_bounds__(128) void k_mean(
    const float* __restrict__ lp, float* __restrict__ out)
{
    __shared__ float red[128];
    const int t = threadIdx.x;
    red[t] = lp[t];
    __syncthreads();
    #pragma unroll
    for (int st = 64; st > 0; st >>= 1) {
        if (t < st) red[t] += red[t + st];
        __syncthreads();
    }
    if (t == 0) out[0] = red[0] / (float)NTOT;
}

extern "C" void kernel_launch(void* const* d_in, const int* in_sizes, int n_in,
                              void* d_out, int out_size, void* d_ws, size_t ws_size,
                              hipStream_t stream) {
    const float* zi = (const float*)d_in[0];
    const float* zj = (const float*)d_in[1];
    const float* W  = (const float*)d_in[2];
    const float* b  = (const float*)d_in[3];

    float* sp      = (float*)d_ws;        // NTOT floats
    float* partial = sp + NTOT;           // NBLK1 floats
    float* lp      = partial + NBLK1;     // NBLK3 floats
    float* total   = lp + NBLK3;          // 1 float
    float* out     = (float*)d_out;

    k_dot_sig<<<NBLK1, 256, 0, stream>>>(zi, zj, W, b, sp, partial);
    k_total <<<1, 1024, 0, stream>>>(partial, total);
    k_loss  <<<NBLK3, 256, 0, stream>>>(sp, total, lp);
    k_mean  <<<1, 128, 0, stream>>>(lp, out);
}